// Round 1
// baseline (190.573 us; speedup 1.0000x reference)
//
#include <hip/hip_runtime.h>
#include <hip/hip_bf16.h>

#define FEATSZ 2048
#define HIDSZ  1024
#define ATTSZ  512
#define BATCH  64
#define FEATN  512

typedef float  f32x4  __attribute__((ext_vector_type(4)));
typedef __bf16 bf16x8 __attribute__((ext_vector_type(8)));

__device__ __forceinline__ unsigned short f2bf(float f) {
    union { float f; unsigned int u; } x; x.f = f;
    unsigned int u = x.u;
    return (unsigned short)((u + 0x7fffu + ((u >> 16) & 1u)) >> 16);
}

// ---------------- K0a: h = key @ wh_w.T + wh_b  (64 x 512) ----------------
__global__ void k_h(const float* __restrict__ key, const float* __restrict__ wh_w,
                    const float* __restrict__ wh_b, float* __restrict__ h) {
    const int b = blockIdx.y;          // batch
    const int ac = blockIdx.x;         // a-chunk of 64
    const int t = threadIdx.x;         // 256
    const int lane = t & 63, wv = t >> 6;
    float k16[16];
    const float* kb = key + b * HIDSZ;
#pragma unroll
    for (int j = 0; j < 16; ++j) k16[j] = kb[lane + 64 * j];
#pragma unroll 1
    for (int i = 0; i < 16; ++i) {
        int a = ac * 64 + wv * 16 + i;
        const float* wr = wh_w + (size_t)a * HIDSZ;
        float s = 0.f;
#pragma unroll
        for (int j = 0; j < 16; ++j) s += k16[j] * wr[lane + 64 * j];
#pragma unroll
        for (int d = 32; d; d >>= 1) s += __shfl_xor(s, d);
        if (lane == 0) h[b * ATTSZ + a] = s + wh_b[a];
    }
}

// ------- K0b: convert wv_w (512x2048 f32) -> bf16 in MFMA-fragment order -------
// dst layout: for (a,k): CF=a>>4, c=a&15, ks=k>>5, kin=k&31
//   idx = ((ks*32+CF)*64 + (c + 16*(kin>>3)))*8 + (kin&7)
__global__ void k_wvcvt(const float* __restrict__ wv_w, unsigned short* __restrict__ wvb) {
    int idx = blockIdx.x * 256 + threadIdx.x;       // < 512*2048
    int a = idx >> 11, k = idx & 2047;
    int CF = a >> 4, c = a & 15, ks = k >> 5, kin = k & 31;
    int lane = c + ((kin >> 3) << 4);
    int dst = ((ks * 32 + CF) * 64 + lane) * 8 + (kin & 7);
    wvb[dst] = f2bf(wv_w[idx]);
}

// ---------------- K1: fused GEMM(feats, wv^T) + tanh·wa -> scores ----------------
// block: 512 thr (8 waves). Mtile=64 rows, full A=512 cols (wave w owns cols [w*64,w*64+64)).
// A staged fp32->bf16 in swizzled LDS (dbuf); B frags loaded straight from relayout'd ws (L2).
__global__ __launch_bounds__(512) void k_scores(
        const float* __restrict__ feats, const unsigned short* __restrict__ wvb,
        const float* __restrict__ h, const float* __restrict__ wv_b,
        const float* __restrict__ wa, float* __restrict__ scores) {
    __shared__ __align__(16) unsigned long long Alds[2][512];  // [buf][row*8+q] swizzled, 8KB
    __shared__ float hb[ATTSZ];
    __shared__ float wal[ATTSZ];
    __shared__ float scp[8][64];

    const int t = threadIdx.x;
    const int lane = t & 63, w = t >> 6;
    const int m0 = blockIdx.x * 64;
    const int b = m0 >> 9;

    hb[t]  = h[b * ATTSZ + t] + wv_b[t];
    wal[t] = wa[t];

    const int row = t >> 3, kq = t & 7;
    const float* gp = feats + (size_t)(m0 + row) * FEATSZ + kq * 4;

    auto stA = [&](int buf, float4 v) {
        unsigned long long u = (unsigned long long)f2bf(v.x)
                             | ((unsigned long long)f2bf(v.y) << 16)
                             | ((unsigned long long)f2bf(v.z) << 32)
                             | ((unsigned long long)f2bf(v.w) << 48);
        int idx8 = (row * 8 + kq) ^ ((row & 7) << 1);   // byte-XOR ((row&7)<<4) in u64 units
        Alds[buf][idx8] = u;
    };

    float4 a0 = *(const float4*)gp;
    stA(0, a0);

    const unsigned short* wb = wvb + w * 2048 + lane * 8;
    bf16x8 bcur[4];
#pragma unroll
    for (int cf = 0; cf < 4; ++cf) bcur[cf] = *(const bf16x8*)(wb + cf * 512);

    const char* abase = (const char*)&Alds[0][0];
    int raddr[4];
#pragma unroll
    for (int m = 0; m < 4; ++m) {
        int r = m * 16 + (lane & 15);
        raddr[m] = ((r * 64) + ((lane >> 4) * 16)) ^ ((r & 7) << 4);
    }

    f32x4 acc[4][4];
#pragma unroll
    for (int m = 0; m < 4; ++m)
#pragma unroll
        for (int cf = 0; cf < 4; ++cf) acc[m][cf] = (f32x4)0.0f;

    __syncthreads();

    int cur = 0;
#pragma unroll 2
    for (int it = 0; it < 64; ++it) {
        float4 anxt;
        bf16x8 bnxt[4];
        if (it < 63) {
            anxt = *(const float4*)(gp + (it + 1) * 32);
            const unsigned short* wbn = wb + (it + 1) * 16384;
#pragma unroll
            for (int cf = 0; cf < 4; ++cf) bnxt[cf] = *(const bf16x8*)(wbn + cf * 512);
        }
        bf16x8 af[4];
#pragma unroll
        for (int m = 0; m < 4; ++m)
            af[m] = *(const bf16x8*)__builtin_assume_aligned(abase + cur * 4096 + raddr[m], 16);
#pragma unroll
        for (int m = 0; m < 4; ++m)
#pragma unroll
            for (int cf = 0; cf < 4; ++cf)
                acc[m][cf] = __builtin_amdgcn_mfma_f32_16x16x32_bf16(af[m], bcur[cf], acc[m][cf], 0, 0, 0);
        if (it < 63) stA(cur ^ 1, anxt);
        __syncthreads();
        if (it < 63) {
#pragma unroll
            for (int cf = 0; cf < 4; ++cf) bcur[cf] = bnxt[cf];
        }
        cur ^= 1;
    }

    // epilogue: p[r] = sum_a tanh(acc + h[b,a] + wv_b[a]) * wa[a]
    float p[4][4];
#pragma unroll
    for (int m = 0; m < 4; ++m)
#pragma unroll
        for (int j = 0; j < 4; ++j) p[m][j] = 0.f;

    const int c = lane & 15, q = lane >> 4;
#pragma unroll
    for (int m = 0; m < 4; ++m)
#pragma unroll
        for (int cf = 0; cf < 4; ++cf) {
            int a = w * 64 + cf * 16 + c;
            float hba = hb[a], waa = wal[a];
#pragma unroll
            for (int j = 0; j < 4; ++j)
                p[m][j] += tanhf(acc[m][cf][j] + hba) * waa;
        }
#pragma unroll
    for (int m = 0; m < 4; ++m)
#pragma unroll
        for (int j = 0; j < 4; ++j) {
            float v = p[m][j];
            v += __shfl_xor(v, 1); v += __shfl_xor(v, 2);
            v += __shfl_xor(v, 4); v += __shfl_xor(v, 8);
            p[m][j] = v;
        }
    if (c == 0) {
#pragma unroll
        for (int m = 0; m < 4; ++m)
#pragma unroll
            for (int j = 0; j < 4; ++j)
                scp[w][m * 16 + q * 4 + j] = p[m][j];
    }
    __syncthreads();
    if (t < 64) {
        float s = 0.f;
#pragma unroll
        for (int ww = 0; ww < 8; ++ww) s += scp[ww][t];
        scores[m0 + t] = s;
    }
}

// ---------------- K2: softmax over N=512 per batch ----------------
__global__ void k_softmax(const float* __restrict__ scores, float* __restrict__ alpha) {
    __shared__ float red[16];
    const int b = blockIdx.x, t = threadIdx.x;     // 512 threads
    const int lane = t & 63, w = t >> 6;
    float s = scores[b * FEATN + t];
    float m = s;
#pragma unroll
    for (int d = 32; d; d >>= 1) m = fmaxf(m, __shfl_xor(m, d));
    if (lane == 0) red[w] = m;
    __syncthreads();
    if (t == 0) {
        float mm = red[0];
        for (int i = 1; i < 8; ++i) mm = fmaxf(mm, red[i]);
        red[8] = mm;
    }
    __syncthreads();
    float e = __expf(s - red[8]);
    float sum = e;
#pragma unroll
    for (int d = 32; d; d >>= 1) sum += __shfl_xor(sum, d);
    if (lane == 0) red[w] = sum;
    __syncthreads();
    if (t == 0) {
        float ss = 0.f;
        for (int i = 0; i < 8; ++i) ss += red[i];
        red[9] = 1.0f / ss;
    }
    __syncthreads();
    alpha[b * FEATN + t] = e * red[9];
}

// ---------------- K3a: partial att_feats over n-slices ----------------
__global__ void k_att_part(const float* __restrict__ feats, const float* __restrict__ alpha,
                           float* __restrict__ part) {
    const int b = blockIdx.x, fc = blockIdx.y, ns = blockIdx.z, t = threadIdx.x;
    const int f0 = fc * 1024 + t * 4;
    const float* fp = feats + (size_t)(b * FEATN + ns * 128) * FEATSZ + f0;
    const float* al = alpha + b * FEATN + ns * 128;
    float4 acc = {0.f, 0.f, 0.f, 0.f};
#pragma unroll 4
    for (int i = 0; i < 128; ++i) {
        float a = al[i];
        float4 v = *(const float4*)(fp + (size_t)i * FEATSZ);
        acc.x += a * v.x; acc.y += a * v.y; acc.z += a * v.z; acc.w += a * v.w;
    }
    *(float4*)(part + ((size_t)ns * BATCH + b) * FEATSZ + f0) = acc;
}

// ---------------- K3b: reduce 4 partials -> att_feats ----------------
__global__ void k_att_red(const float* __restrict__ part, float* __restrict__ out) {
    const int idx = (blockIdx.x * 256 + threadIdx.x) * 4;   // < 131072
    float4 s = *(const float4*)(part + idx);
#pragma unroll
    for (int z = 1; z < 4; ++z) {
        float4 v = *(const float4*)(part + (size_t)z * (BATCH * FEATSZ) + idx);
        s.x += v.x; s.y += v.y; s.z += v.z; s.w += v.w;
    }
    *(float4*)(out + idx) = s;
}

extern "C" void kernel_launch(void* const* d_in, const int* in_sizes, int n_in,
                              void* d_out, int out_size, void* d_ws, size_t ws_size,
                              hipStream_t stream) {
    const float* feats = (const float*)d_in[0];
    const float* key   = (const float*)d_in[1];
    const float* wh_w  = (const float*)d_in[2];
    const float* wh_b  = (const float*)d_in[3];
    const float* wv_w  = (const float*)d_in[4];
    const float* wv_b  = (const float*)d_in[5];
    const float* wa_w  = (const float*)d_in[6];

    float* out_att   = (float*)d_out;                 // 64*2048
    float* out_alpha = out_att + BATCH * FEATSZ;      // 64*512

    char* ws = (char*)d_ws;
    float* h              = (float*)(ws);             // 128 KB
    float* scores         = (float*)(ws + 131072);    // 128 KB
    unsigned short* wvb   = (unsigned short*)(ws + 262144);  // 2 MB (used by K0b/K1)
    float* part           = (float*)(ws + 262144);    // 2 MB (reuses wvb region after K1)

    hipLaunchKernelGGL(k_h,        dim3(8, 64),    dim3(256), 0, stream, key, wh_w, wh_b, h);
    hipLaunchKernelGGL(k_wvcvt,    dim3(4096),     dim3(256), 0, stream, wv_w, wvb);
    hipLaunchKernelGGL(k_scores,   dim3(512),      dim3(512), 0, stream, feats, wvb, h, wv_b, wa_w, scores);
    hipLaunchKernelGGL(k_softmax,  dim3(64),       dim3(512), 0, stream, scores, out_alpha);
    hipLaunchKernelGGL(k_att_part, dim3(64, 2, 4), dim3(256), 0, stream, feats, out_alpha, part);
    hipLaunchKernelGGL(k_att_red,  dim3(128),      dim3(256), 0, stream, part, out_att);
}

// Round 2
// 174.133 us; speedup vs baseline: 1.0944x; 1.0944x over previous
//
#include <hip/hip_runtime.h>
#include <hip/hip_bf16.h>

#define FEATSZ 2048
#define HIDSZ  1024
#define ATTSZ  512
#define BATCH  64
#define FEATN  512

typedef float  f32x4  __attribute__((ext_vector_type(4)));
typedef __bf16 bf16x8 __attribute__((ext_vector_type(8)));

__device__ __forceinline__ unsigned short f2bf(float f) {
    union { float f; unsigned int u; } x; x.f = f;
    unsigned int u = x.u;
    return (unsigned short)((u + 0x7fffu + ((u >> 16) & 1u)) >> 16);
}

// ---------------- K0a: h = key @ wh_w.T + wh_b  (64 x 512) ----------------
__global__ void k_h(const float* __restrict__ key, const float* __restrict__ wh_w,
                    const float* __restrict__ wh_b, float* __restrict__ h) {
    const int b = blockIdx.y;
    const int ac = blockIdx.x;
    const int t = threadIdx.x;         // 256
    const int lane = t & 63, wv = t >> 6;
    float k16[16];
    const float* kb = key + b * HIDSZ;
#pragma unroll
    for (int j = 0; j < 16; ++j) k16[j] = kb[lane + 64 * j];
#pragma unroll 1
    for (int i = 0; i < 16; ++i) {
        int a = ac * 64 + wv * 16 + i;
        const float* wr = wh_w + (size_t)a * HIDSZ;
        float s = 0.f;
#pragma unroll
        for (int j = 0; j < 16; ++j) s += k16[j] * wr[lane + 64 * j];
#pragma unroll
        for (int d = 32; d; d >>= 1) s += __shfl_xor(s, d);
        if (lane == 0) h[b * ATTSZ + a] = s + wh_b[a];
    }
}

// ------- K0b: convert wv_w (512x2048 f32) -> bf16 in MFMA-fragment order -------
__global__ void k_wvcvt(const float* __restrict__ wv_w, unsigned short* __restrict__ wvb) {
    int idx = blockIdx.x * 256 + threadIdx.x;       // < 512*2048
    int a = idx >> 11, k = idx & 2047;
    int CF = a >> 4, c = a & 15, ks = k >> 5, kin = k & 31;
    int lane = c + ((kin >> 3) << 4);
    int dst = ((ks * 32 + CF) * 64 + lane) * 8 + (kin & 7);
    wvb[dst] = f2bf(wv_w[idx]);
}

// ---------------- K1: fused GEMM(feats, wv^T) + tanh·wa -> scores ----------------
// 512 thr (8 waves), Mtile=64, BK=128, 16 iters. A staged fp32 via global_load_lds
// (linear LDS dest, inverse-XOR-swizzled global source), read back swizzled as
// 2x ds_read_b128 + v_cvt_pk_bf16_f32. B frags straight from relayout'd ws (L2).
__global__ __launch_bounds__(512, 4) void k_scores(
        const float* __restrict__ feats, const unsigned short* __restrict__ wvb,
        const float* __restrict__ h, const float* __restrict__ wv_b,
        const float* __restrict__ wa, float* __restrict__ scores) {
    __shared__ __align__(16) char smem[65536];      // A dbuf: 2 x [64 rows][128 k] f32
    const int t = threadIdx.x;
    const int lane = t & 63, w = t >> 6;
    const int m0 = blockIdx.x * 64;
    const int b = m0 >> 9;

    // Staging: wave w, instr s covers LDS chunks q = w*256 + s*64 + lane (16B units).
    // Storage def: chunk q holds logical (row r = q>>5, k-chunk c = (q&31) ^ (r&7)).
    const char* fbase = (const char*)feats;
    unsigned int goff[4];   // per-lane global byte offset (add it*512 per iter)
    unsigned int ldst[4];   // wave-uniform LDS byte base per staging instr
#pragma unroll
    for (int s = 0; s < 4; ++s) {
        int q = w * 256 + s * 64 + lane;
        int r = q >> 5;
        int c = (q & 31) ^ (r & 7);
        goff[s] = (unsigned int)(((m0 + r) * 2048 + c * 4) * 4);
        ldst[s] = (unsigned int)(w * 4096 + s * 1024);
    }

    // Read addrs: row r = m*16 + (lane&15) (r&7 == lane&7), chunks (ks*8+2k8)^r7, +1^r7
    const int A0 = (lane & 15) * 512 + ((((lane >> 4) * 2)    ) ^ (lane & 7)) * 16;
    const int A1 = (lane & 15) * 512 + ((((lane >> 4) * 2) | 1) ^ (lane & 7)) * 16;

    auto stage = [&](int bufc, int it) {
#pragma unroll
        for (int s = 0; s < 4; ++s)
            __builtin_amdgcn_global_load_lds(
                (const __attribute__((address_space(1))) void*)(fbase + goff[s] + it * 512),
                (__attribute__((address_space(3))) void*)(smem + bufc * 32768 + ldst[s]),
                16, 0, 0);
    };

    const unsigned short* wb = wvb + w * 2048 + lane * 8;
    bf16x8 bn[4];
    auto loadB = [&](int kk) {
#pragma unroll
        for (int cf = 0; cf < 4; ++cf) bn[cf] = *(const bf16x8*)(wb + kk * 16384 + cf * 512);
    };

    f32x4 acc[4][4];
#pragma unroll
    for (int m = 0; m < 4; ++m)
#pragma unroll
        for (int cf = 0; cf < 4; ++cf) acc[m][cf] = (f32x4)0.0f;

    stage(0, 0);
    loadB(0);
    __syncthreads();

    auto kiter = [&](int it, int bufc) {
        if (it < 15) stage(bufc ^ 1, it + 1);
#pragma unroll
        for (int ks = 0; ks < 4; ++ks) {
            bf16x8 bc[4];
#pragma unroll
            for (int cf = 0; cf < 4; ++cf) bc[cf] = bn[cf];
            int kk = it * 4 + ks + 1; if (kk > 63) kk = 63;
            loadB(kk);
#pragma unroll
            for (int m = 0; m < 4; ++m) {
                const char* ap = (const char*)smem + bufc * 32768 + m * 8192 + ks * 128;
                f32x4 fa = *(const f32x4*)(ap + A0);
                f32x4 fb = *(const f32x4*)(ap + A1);
                unsigned int q0, q1, q2, q3;
                asm("v_cvt_pk_bf16_f32 %0, %1, %2" : "=v"(q0) : "v"(fa.x), "v"(fa.y));
                asm("v_cvt_pk_bf16_f32 %0, %1, %2" : "=v"(q1) : "v"(fa.z), "v"(fa.w));
                asm("v_cvt_pk_bf16_f32 %0, %1, %2" : "=v"(q2) : "v"(fb.x), "v"(fb.y));
                asm("v_cvt_pk_bf16_f32 %0, %1, %2" : "=v"(q3) : "v"(fb.z), "v"(fb.w));
                union { unsigned int u[4]; bf16x8 v; } af;
                af.u[0] = q0; af.u[1] = q1; af.u[2] = q2; af.u[3] = q3;
#pragma unroll
                for (int cf = 0; cf < 4; ++cf)
                    acc[m][cf] = __builtin_amdgcn_mfma_f32_16x16x32_bf16(af.v, bc[cf], acc[m][cf], 0, 0, 0);
            }
        }
        __syncthreads();
    };

#pragma unroll 1
    for (int it2 = 0; it2 < 8; ++it2) {
        kiter(it2 * 2, 0);
        kiter(it2 * 2 + 1, 1);
    }

    // epilogue: p[r] = sum_a tanh(acc + h[b,a] + wv_b[a]) * wa[a]
    const int c16 = lane & 15, q4 = lane >> 4;
    float hreg[4], wreg[4];
#pragma unroll
    for (int cf = 0; cf < 4; ++cf) {
        int a = w * 64 + cf * 16 + c16;
        hreg[cf] = h[b * ATTSZ + a] + wv_b[a];
        wreg[cf] = wa[a];
    }
    float p[4][4];
#pragma unroll
    for (int m = 0; m < 4; ++m)
#pragma unroll
        for (int j = 0; j < 4; ++j) p[m][j] = 0.f;
#pragma unroll
    for (int m = 0; m < 4; ++m)
#pragma unroll
        for (int cf = 0; cf < 4; ++cf) {
#pragma unroll
            for (int j = 0; j < 4; ++j)
                p[m][j] += tanhf(acc[m][cf][j] + hreg[cf]) * wreg[cf];
        }
#pragma unroll
    for (int m = 0; m < 4; ++m)
#pragma unroll
        for (int j = 0; j < 4; ++j) {
            float v = p[m][j];
            v += __shfl_xor(v, 1); v += __shfl_xor(v, 2);
            v += __shfl_xor(v, 4); v += __shfl_xor(v, 8);
            p[m][j] = v;
        }
    float* scp = (float*)smem;   // alias A-tile (all A reads done: loop ends with barrier)
    if (c16 == 0) {
#pragma unroll
        for (int m = 0; m < 4; ++m)
#pragma unroll
            for (int j = 0; j < 4; ++j)
                scp[w * 64 + m * 16 + q4 * 4 + j] = p[m][j];
    }
    __syncthreads();
    if (t < 64) {
        float s = 0.f;
#pragma unroll
        for (int ww = 0; ww < 8; ++ww) s += scp[ww * 64 + t];
        scores[m0 + t] = s;
    }
}

// ---------------- K2: softmax over N=512 per batch ----------------
__global__ void k_softmax(const float* __restrict__ scores, float* __restrict__ alpha) {
    __shared__ float red[16];
    const int b = blockIdx.x, t = threadIdx.x;     // 512 threads
    const int lane = t & 63, w = t >> 6;
    float s = scores[b * FEATN + t];
    float m = s;
#pragma unroll
    for (int d = 32; d; d >>= 1) m = fmaxf(m, __shfl_xor(m, d));
    if (lane == 0) red[w] = m;
    __syncthreads();
    if (t == 0) {
        float mm = red[0];
        for (int i = 1; i < 8; ++i) mm = fmaxf(mm, red[i]);
        red[8] = mm;
    }
    __syncthreads();
    float e = __expf(s - red[8]);
    float sum = e;
#pragma unroll
    for (int d = 32; d; d >>= 1) sum += __shfl_xor(sum, d);
    if (lane == 0) red[w] = sum;
    __syncthreads();
    if (t == 0) {
        float ss = 0.f;
        for (int i = 0; i < 8; ++i) ss += red[i];
        red[9] = 1.0f / ss;
    }
    __syncthreads();
    alpha[b * FEATN + t] = e * red[9];
}

// ---------------- K3a: partial att_feats over n-slices ----------------
__global__ void k_att_part(const float* __restrict__ feats, const float* __restrict__ alpha,
                           float* __restrict__ part) {
    const int b = blockIdx.x, fc = blockIdx.y, ns = blockIdx.z, t = threadIdx.x;
    const int f0 = fc * 1024 + t * 4;
    const float* fp = feats + (size_t)(b * FEATN + ns * 128) * FEATSZ + f0;
    const float* al = alpha + b * FEATN + ns * 128;
    float4 acc = {0.f, 0.f, 0.f, 0.f};
#pragma unroll 4
    for (int i = 0; i < 128; ++i) {
        float a = al[i];
        float4 v = *(const float4*)(fp + (size_t)i * FEATSZ);
        acc.x += a * v.x; acc.y += a * v.y; acc.z += a * v.z; acc.w += a * v.w;
    }
    *(float4*)(part + ((size_t)ns * BATCH + b) * FEATSZ + f0) = acc;
}

// ---------------- K3b: reduce 4 partials -> att_feats ----------------
__global__ void k_att_red(const float* __restrict__ part, float* __restrict__ out) {
    const int idx = (blockIdx.x * 256 + threadIdx.x) * 4;   // < 131072
    float4 s = *(const float4*)(part + idx);
#pragma unroll
    for (int z = 1; z < 4; ++z) {
        float4 v = *(const float4*)(part + (size_t)z * (BATCH * FEATSZ) + idx);
        s.x += v.x; s.y += v.y; s.z += v.z; s.w += v.w;
    }
    *(float4*)(out + idx) = s;
}

extern "C" void kernel_launch(void* const* d_in, const int* in_sizes, int n_in,
                              void* d_out, int out_size, void* d_ws, size_t ws_size,
                              hipStream_t stream) {
    const float* feats = (const float*)d_in[0];
    const float* key   = (const float*)d_in[1];
    const float* wh_w  = (const float*)d_in[2];
    const float* wh_b  = (const float*)d_in[3];
    const float* wv_w  = (const float*)d_in[4];
    const float* wv_b  = (const float*)d_in[5];
    const float* wa_w  = (const float*)d_in[6];

    float* out_att   = (float*)d_out;                 // 64*2048
    float* out_alpha = out_att + BATCH * FEATSZ;      // 64*512

    char* ws = (char*)d_ws;
    float* h              = (float*)(ws);             // 128 KB
    float* scores         = (float*)(ws + 131072);    // 128 KB
    unsigned short* wvb   = (unsigned short*)(ws + 262144);  // 2 MB (used by K0b/K1)
    float* part           = (float*)(ws + 262144);    // 2 MB (reuses wvb region after K1)

    hipLaunchKernelGGL(k_h,        dim3(8, 64),    dim3(256), 0, stream, key, wh_w, wh_b, h);
    hipLaunchKernelGGL(k_wvcvt,    dim3(4096),     dim3(256), 0, stream, wv_w, wvb);
    hipLaunchKernelGGL(k_scores,   dim3(512),      dim3(512), 0, stream, feats, wvb, h, wv_b, wa_w, scores);
    hipLaunchKernelGGL(k_softmax,  dim3(64),       dim3(512), 0, stream, scores, out_alpha);
    hipLaunchKernelGGL(k_att_part, dim3(64, 2, 4), dim3(256), 0, stream, feats, out_alpha, part);
    hipLaunchKernelGGL(k_att_red,  dim3(128),      dim3(256), 0, stream, part, out_att);
}

// Round 3
// 164.058 us; speedup vs baseline: 1.1616x; 1.0614x over previous
//
#include <hip/hip_runtime.h>
#include <hip/hip_bf16.h>

#define FEATSZ 2048
#define HIDSZ  1024
#define ATTSZ  512
#define BATCH  64
#define FEATN  512

typedef float  f32x4  __attribute__((ext_vector_type(4)));
typedef __bf16 bf16x8 __attribute__((ext_vector_type(8)));

__device__ __forceinline__ unsigned short f2bf(float f) {
    union { float f; unsigned int u; } x; x.f = f;
    unsigned int u = x.u;
    return (unsigned short)((u + 0x7fffu + ((u >> 16) & 1u)) >> 16);
}

// ---------------- K0a: h = key @ wh_w.T + wh_b  (64 x 512) ----------------
__global__ void k_h(const float* __restrict__ key, const float* __restrict__ wh_w,
                    const float* __restrict__ wh_b, float* __restrict__ h) {
    const int b = blockIdx.y;
    const int ac = blockIdx.x;
    const int t = threadIdx.x;         // 256
    const int lane = t & 63, wv = t >> 6;
    float k16[16];
    const float* kb = key + b * HIDSZ;
#pragma unroll
    for (int j = 0; j < 16; ++j) k16[j] = kb[lane + 64 * j];
#pragma unroll 1
    for (int i = 0; i < 16; ++i) {
        int a = ac * 64 + wv * 16 + i;
        const float* wr = wh_w + (size_t)a * HIDSZ;
        float s = 0.f;
#pragma unroll
        for (int j = 0; j < 16; ++j) s += k16[j] * wr[lane + 64 * j];
#pragma unroll
        for (int d = 32; d; d >>= 1) s += __shfl_xor(s, d);
        if (lane == 0) h[b * ATTSZ + a] = s + wh_b[a];
    }
}

// ------- K0b: convert wv_w (512x2048 f32) -> bf16 in MFMA-fragment order -------
__global__ void k_wvcvt(const float* __restrict__ wv_w, unsigned short* __restrict__ wvb) {
    int idx = blockIdx.x * 256 + threadIdx.x;       // < 512*2048
    int a = idx >> 11, k = idx & 2047;
    int CF = a >> 4, c = a & 15, ks = k >> 5, kin = k & 31;
    int lane = c + ((kin >> 3) << 4);
    int dst = ((ks * 32 + CF) * 64 + lane) * 8 + (kin & 7);
    wvb[dst] = f2bf(wv_w[idx]);
}

// ---------------- K1: fused GEMM(feats, wv^T) + tanh·wa -> scores ----------------
// 256 blocks (1/CU), 8 waves. Mtile=128, BK=64, 32 kiters. Wave w owns ALL 128
// rows x 64 a-cols [w*64, w*64+64) -> disjoint B slices (per-block B = 2MB once).
// A fp32 staged via global_load_lds into XOR-swizzled LDS dbuf; B reg-dbuf from L2.
__global__ __launch_bounds__(512, 2) void k_scores(
        const float* __restrict__ feats, const unsigned short* __restrict__ wvb,
        const float* __restrict__ h, const float* __restrict__ wv_b,
        const float* __restrict__ wa, float* __restrict__ scores) {
    __shared__ __align__(16) char smem[65536];      // A dbuf: 2 x [128 rows][64 k] f32
    const int t = threadIdx.x;
    const int lane = t & 63, w = t >> 6;
    const int m0 = blockIdx.x * 128;
    const int b = blockIdx.x >> 2;                  // 4 blocks per batch

    // ---- A staging: block tile = 128 rows x 64 k f32 = 32KB = 2048 x 16B chunks.
    // Storage: chunk q -> (row r=q>>4, slot cs=q&15) holds logical k-chunk c = cs^(r&7).
    const char* fbase = (const char*)feats;
    unsigned int goff[4], ldst[4];
#pragma unroll
    for (int s = 0; s < 4; ++s) {
        int q = w * 256 + s * 64 + lane;
        int r = q >> 4, c = (q & 15) ^ (r & 7);
        goff[s] = (unsigned int)(((m0 + r) * 2048 + c * 4) * 4);
        ldst[s] = (unsigned int)(w * 4096 + s * 1024);
    }
    auto stage = [&](int buf, int it) {
#pragma unroll
        for (int s = 0; s < 4; ++s)
            __builtin_amdgcn_global_load_lds(
                (const __attribute__((address_space(1))) void*)(fbase + goff[s] + it * 256),
                (__attribute__((address_space(3))) void*)(smem + buf * 32768 + ldst[s]),
                16, 0, 0);
    };

    // ---- B: 4 frags per ks from relayout'd wvb (L2-resident), reg double-buffer.
    const unsigned short* wb = wvb + lane * 8;
    bf16x8 bnA[4], bnB[4];
    auto loadBA = [&](int kk) {
#pragma unroll
        for (int cf = 0; cf < 4; ++cf) bnA[cf] = *(const bf16x8*)(wb + (kk * 32 + w * 4 + cf) * 512);
    };
    auto loadBB = [&](int kk) {
#pragma unroll
        for (int cf = 0; cf < 4; ++cf) bnB[cf] = *(const bf16x8*)(wb + (kk * 32 + w * 4 + cf) * 512);
    };

    // ---- swizzled A read offsets: row r = m*16 + (lane&15), chunks (ks*8+kq*2)^{,+1}^(r&7)
    const int sw = lane & 7, kq2 = (lane >> 4) * 2;
    const int off0 = (lane & 15) * 256 + ((kq2    ) ^ sw) * 16;
    const int off1 = (lane & 15) * 256 + ((kq2 | 1) ^ sw) * 16;

    f32x4 acc[8][4];
#pragma unroll
    for (int m = 0; m < 8; ++m)
#pragma unroll
        for (int cf = 0; cf < 4; ++cf) acc[m][cf] = (f32x4)0.0f;

    stage(0, 0);
    loadBA(0);
    __syncthreads();

    auto domfmaA = [&](int buf, int ks) {
#pragma unroll
        for (int m = 0; m < 8; ++m) {
            const char* ap = smem + buf * 32768 + m * 4096 + ks * 128;
            f32x4 fa = *(const f32x4*)__builtin_assume_aligned(ap + off0, 16);
            f32x4 fb = *(const f32x4*)__builtin_assume_aligned(ap + off1, 16);
            bf16x8 af;
            af[0] = (__bf16)fa[0]; af[1] = (__bf16)fa[1]; af[2] = (__bf16)fa[2]; af[3] = (__bf16)fa[3];
            af[4] = (__bf16)fb[0]; af[5] = (__bf16)fb[1]; af[6] = (__bf16)fb[2]; af[7] = (__bf16)fb[3];
#pragma unroll
            for (int cf = 0; cf < 4; ++cf)
                acc[m][cf] = __builtin_amdgcn_mfma_f32_16x16x32_bf16(af, bnA[cf], acc[m][cf], 0, 0, 0);
        }
    };
    auto domfmaB = [&](int buf, int ks) {
#pragma unroll
        for (int m = 0; m < 8; ++m) {
            const char* ap = smem + buf * 32768 + m * 4096 + ks * 128;
            f32x4 fa = *(const f32x4*)__builtin_assume_aligned(ap + off0, 16);
            f32x4 fb = *(const f32x4*)__builtin_assume_aligned(ap + off1, 16);
            bf16x8 af;
            af[0] = (__bf16)fa[0]; af[1] = (__bf16)fa[1]; af[2] = (__bf16)fa[2]; af[3] = (__bf16)fa[3];
            af[4] = (__bf16)fb[0]; af[5] = (__bf16)fb[1]; af[6] = (__bf16)fb[2]; af[7] = (__bf16)fb[3];
#pragma unroll
            for (int cf = 0; cf < 4; ++cf)
                acc[m][cf] = __builtin_amdgcn_mfma_f32_16x16x32_bf16(af, bnB[cf], acc[m][cf], 0, 0, 0);
        }
    };

#pragma unroll 1
    for (int it = 0; it < 32; ++it) {
        const int buf = it & 1;
        if (it < 31) stage(buf ^ 1, it + 1);
        loadBB(2 * it + 1);                      // prefetch ks=1's B
        domfmaA(buf, 0);                         // consume bnA (kk=2*it)
        loadBA(2 * it + 2 > 63 ? 63 : 2 * it + 2);  // prefetch next kiter's ks=0
        domfmaB(buf, 1);                         // consume bnB (kk=2*it+1)
        __syncthreads();
    }

    // ---- epilogue: p[r] = sum_a tanh(acc + h[b,a] + wv_b[a]) * wa[a]
    const int c16 = lane & 15, q4 = lane >> 4;
    float hreg[4], wreg[4];
#pragma unroll
    for (int cf = 0; cf < 4; ++cf) {
        int a = w * 64 + cf * 16 + c16;
        hreg[cf] = h[b * ATTSZ + a] + wv_b[a];
        wreg[cf] = wa[a];
    }
    float p[8][4];
#pragma unroll
    for (int m = 0; m < 8; ++m)
#pragma unroll
        for (int j = 0; j < 4; ++j) p[m][j] = 0.f;
#pragma unroll
    for (int m = 0; m < 8; ++m)
#pragma unroll
        for (int cf = 0; cf < 4; ++cf)
#pragma unroll
            for (int j = 0; j < 4; ++j)
                p[m][j] += tanhf(acc[m][cf][j] + hreg[cf]) * wreg[cf];
#pragma unroll
    for (int m = 0; m < 8; ++m)
#pragma unroll
        for (int j = 0; j < 4; ++j) {
            float v = p[m][j];
            v += __shfl_xor(v, 1); v += __shfl_xor(v, 2);
            v += __shfl_xor(v, 4); v += __shfl_xor(v, 8);
            p[m][j] = v;
        }
    float* scp = (float*)smem;   // alias A-tile (loop ended with barrier)
    if (c16 == 0) {
#pragma unroll
        for (int m = 0; m < 8; ++m)
#pragma unroll
            for (int j = 0; j < 4; ++j)
                scp[w * 128 + m * 16 + q4 * 4 + j] = p[m][j];
    }
    __syncthreads();
    if (t < 128) {
        float s = 0.f;
#pragma unroll
        for (int ww = 0; ww < 8; ++ww) s += scp[ww * 128 + t];
        scores[m0 + t] = s;
    }
}

// ---------------- K2: softmax over N=512 per batch ----------------
__global__ void k_softmax(const float* __restrict__ scores, float* __restrict__ alpha) {
    __shared__ float red[16];
    const int b = blockIdx.x, t = threadIdx.x;     // 512 threads
    const int lane = t & 63, w = t >> 6;
    float s = scores[b * FEATN + t];
    float m = s;
#pragma unroll
    for (int d = 32; d; d >>= 1) m = fmaxf(m, __shfl_xor(m, d));
    if (lane == 0) red[w] = m;
    __syncthreads();
    if (t == 0) {
        float mm = red[0];
        for (int i = 1; i < 8; ++i) mm = fmaxf(mm, red[i]);
        red[8] = mm;
    }
    __syncthreads();
    float e = __expf(s - red[8]);
    float sum = e;
#pragma unroll
    for (int d = 32; d; d >>= 1) sum += __shfl_xor(sum, d);
    if (lane == 0) red[w] = sum;
    __syncthreads();
    if (t == 0) {
        float ss = 0.f;
        for (int i = 0; i < 8; ++i) ss += red[i];
        red[9] = 1.0f / ss;
    }
    __syncthreads();
    alpha[b * FEATN + t] = e * red[9];
}

// ---------------- K3a: partial att_feats over n-slices ----------------
__global__ void k_att_part(const float* __restrict__ feats, const float* __restrict__ alpha,
                           float* __restrict__ part) {
    const int b = blockIdx.x, fc = blockIdx.y, ns = blockIdx.z, t = threadIdx.x;
    const int f0 = fc * 1024 + t * 4;
    const float* fp = feats + (size_t)(b * FEATN + ns * 128) * FEATSZ + f0;
    const float* al = alpha + b * FEATN + ns * 128;
    float4 acc = {0.f, 0.f, 0.f, 0.f};
#pragma unroll 4
    for (int i = 0; i < 128; ++i) {
        float a = al[i];
        float4 v = *(const float4*)(fp + (size_t)i * FEATSZ);
        acc.x += a * v.x; acc.y += a * v.y; acc.z += a * v.z; acc.w += a * v.w;
    }
    *(float4*)(part + ((size_t)ns * BATCH + b) * FEATSZ + f0) = acc;
}

// ---------------- K3b: reduce 4 partials -> att_feats ----------------
__global__ void k_att_red(const float* __restrict__ part, float* __restrict__ out) {
    const int idx = (blockIdx.x * 256 + threadIdx.x) * 4;   // < 131072
    float4 s = *(const float4*)(part + idx);
#pragma unroll
    for (int z = 1; z < 4; ++z) {
        float4 v = *(const float4*)(part + (size_t)z * (BATCH * FEATSZ) + idx);
        s.x += v.x; s.y += v.y; s.z += v.z; s.w += v.w;
    }
    *(float4*)(out + idx) = s;
}

extern "C" void kernel_launch(void* const* d_in, const int* in_sizes, int n_in,
                              void* d_out, int out_size, void* d_ws, size_t ws_size,
                              hipStream_t stream) {
    const float* feats = (const float*)d_in[0];
    const float* key   = (const float*)d_in[1];
    const float* wh_w  = (const float*)d_in[2];
    const float* wh_b  = (const float*)d_in[3];
    const float* wv_w  = (const float*)d_in[4];
    const float* wv_b  = (const float*)d_in[5];
    const float* wa_w  = (const float*)d_in[6];

    float* out_att   = (float*)d_out;                 // 64*2048
    float* out_alpha = out_att + BATCH * FEATSZ;      // 64*512

    char* ws = (char*)d_ws;
    float* h              = (float*)(ws);             // 128 KB
    float* scores         = (float*)(ws + 131072);    // 128 KB
    unsigned short* wvb   = (unsigned short*)(ws + 262144);  // 2 MB (used by K0b/K1)
    float* part           = (float*)(ws + 262144);    // 2 MB (reuses wvb region after K1)

    hipLaunchKernelGGL(k_h,        dim3(8, 64),    dim3(256), 0, stream, key, wh_w, wh_b, h);
    hipLaunchKernelGGL(k_wvcvt,    dim3(4096),     dim3(256), 0, stream, wv_w, wvb);
    hipLaunchKernelGGL(k_scores,   dim3(256),      dim3(512), 0, stream, feats, wvb, h, wv_b, wa_w, scores);
    hipLaunchKernelGGL(k_softmax,  dim3(64),       dim3(512), 0, stream, scores, out_alpha);
    hipLaunchKernelGGL(k_att_part, dim3(64, 2, 4), dim3(256), 0, stream, feats, out_alpha, part);
    hipLaunchKernelGGL(k_att_red,  dim3(128),      dim3(256), 0, stream, part, out_att);
}